// Round 9
// baseline (285.235 us; speedup 1.0000x reference)
//
#include <hip/hip_runtime.h>
#include <stdint.h>

// SR-GNN fused, R9: T_block cuts. (1) gi+gh interleaved in P3 for ILP;
// (2) gi kk=0 B-frags prefetched before the P2 barrier; (3) P4 dots split
// across thread halves (seg=t>>7) so no half-block idles; P4 scratch aliased
// into dead sX. R8 insight: occupancy is quantization-bound (4 blocks/CU of
// work, 2-3 slots -> 2 rounds either way); only per-block latency matters.

#define BDIM 256
#define NB   1024
#define NN   64
#define HH   128
#define SH_STR 136   // u16 stride; 272B rows
#define SX_STR 264   // u16 stride; 528B rows

// d_ws fragment-layout offsets (u16 units)
#define OFS_WIN  0         // w_in : 8 tr x 4 kc x 64 lanes x 8  = 16384
#define OFS_WOUT 16384     // w_out: 16384
#define OFS_WI   32768     // wi   : 24 tr x 8 kc x 64 x 8       = 98304
#define OFS_WH   131072    // wh   : 24 tr x 4 kc x 64 x 8       = 49152
#define OFS_W2   180224    // w2   : 8 tr x 4 kc x 64 x 8        = 16384
#define N_FRAGS  24576     // total frags (16B each) = 384 KB

typedef short v8s __attribute__((ext_vector_type(8)));
typedef float v4f __attribute__((ext_vector_type(4)));

__device__ __forceinline__ float b2f_lo(uint32_t u){
  union { uint32_t u; float f; } v; v.u = u << 16; return v.f;
}
__device__ __forceinline__ float b2f_hi(uint32_t u){
  union { uint32_t u; float f; } v; v.u = u & 0xffff0000u; return v.f;
}
__device__ __forceinline__ uint16_t f2b(float f){   // RNE
  union { float f; uint32_t u; } v; v.f = f;
  uint32_t r = v.u + 0x7fffu + ((v.u >> 16) & 1u);
  return (uint16_t)(r >> 16);
}
__device__ __forceinline__ float b2f(uint16_t s){
  union { uint32_t u; float f; } v; v.u = ((uint32_t)s) << 16; return v.f;
}
__device__ __forceinline__ float sig_f(float x){ return 1.0f / (1.0f + __expf(-x)); }
__device__ __forceinline__ float tanh_f(float x){ return 1.0f - 2.0f / (__expf(2.0f*x) + 1.0f); }

__device__ __forceinline__ uint32_t pack2bf(float a, float b){
  union { float f; uint32_t u; } ua, ub; ua.f = a; ub.f = b;
  return __builtin_amdgcn_perm(ub.u + 0x8000u, ua.u + 0x8000u, 0x07060302u);
}

__device__ __forceinline__ v8s pack8(const float* __restrict__ p){
  float4 f0 = *reinterpret_cast<const float4*>(p);
  float4 f1 = *reinterpret_cast<const float4*>(p + 4);
  union { uint32_t u[4]; v8s v; } o;
  o.u[0] = pack2bf(f0.x, f0.y);
  o.u[1] = pack2bf(f0.z, f0.w);
  o.u[2] = pack2bf(f1.x, f1.y);
  o.u[3] = pack2bf(f1.z, f1.w);
  return o.v;
}

__device__ __forceinline__ v8s ldsA(const uint16_t* buf, int stride,
                                    int row_base, int k_base, int r, int q){
  return *reinterpret_cast<const v8s*>(&buf[(row_base + r) * stride + k_base + q * 8]);
}

__device__ __forceinline__ v8s ldfrag(const uint16_t* __restrict__ ws,
                                      int base, int tile, int lane){
  return *reinterpret_cast<const v8s*>(ws + base + (((size_t)tile * 64 + lane) << 3));
}

#define MFMA(a, b, c) __builtin_amdgcn_mfma_f32_16x16x32_bf16((a), (b), (c), 0, 0, 0)

// ---------------- pre-pass: pack weights into frag layout ----------------
__global__ __launch_bounds__(256) void pack_weights(
    const float* __restrict__ w_in, const float* __restrict__ w_out,
    const float* __restrict__ wi,   const float* __restrict__ wh,
    const float* __restrict__ w2,   uint16_t* __restrict__ ws)
{
  int gid = blockIdx.x * blockDim.x + threadIdx.x;
  if (gid >= N_FRAGS) return;
  const float* W; int C; int fi; int base;
  if (gid < 2048)       { W = w_in;  C = 128; fi = gid;         base = OFS_WIN; }
  else if (gid < 4096)  { W = w_out; C = 128; fi = gid - 2048;  base = OFS_WOUT; }
  else if (gid < 16384) { W = wi;    C = 256; fi = gid - 4096;  base = OFS_WI; }
  else if (gid < 22528) { W = wh;    C = 128; fi = gid - 16384; base = OFS_WH; }
  else                  { W = w2;    C = 128; fi = gid - 22528; base = OFS_W2; }
  int lane = fi & 63;
  int tile = fi >> 6;
  int tc   = C >> 5;
  int tr   = tile / tc, kc = tile - tr * tc;
  int r = lane & 15, q = lane >> 4;
  const float* p = W + (size_t)(tr * 16 + r) * C + kc * 32 + q * 8;
  *reinterpret_cast<v8s*>(ws + base + ((size_t)fi << 3)) = pack8(p);
}

// ---------------- main kernel ----------------
__global__ __launch_bounds__(BDIM, 3) void srgnn_kernel(
    const float* __restrict__ A,
    const int*   __restrict__ items,
    const int*   __restrict__ mask,
    const int*   __restrict__ alias_input,
    const float* __restrict__ emb,
    const float* __restrict__ b_in,  const float* __restrict__ b_out,
    const float* __restrict__ b_iah, const float* __restrict__ b_oah,
    const float* __restrict__ bi,    const float* __restrict__ bh,
    const float* __restrict__ w1,    const float* __restrict__ b1,
    const float* __restrict__ b2,
    const float* __restrict__ wq,
    const float* __restrict__ w3,    const float* __restrict__ b3,
    const uint16_t* __restrict__ ws,
    float* __restrict__ out)
{
  __shared__ __align__(16) uint16_t sH[NN * SH_STR];   // hidden bf16, 17.0 KB
  __shared__ __align__(16) uint16_t sX[NN * SX_STR];   // ie bf16 / P4 scratch, 33.0 KB
  __shared__ int sAliasRow[64], sMaskArr[64];

  // P4 float scratch aliased into sX (dead after last P3)
  float* sF      = reinterpret_cast<float*>(sX);
  float* sQ1v    = sF;          // 128
  float* sGlobv  = sF + 128;    // 128
  float* sAPartv = sF + 256;    // 4*64
  float* sAlphav = sF + 512;    // 64
  float* sP      = sF + 576;    // 2*128 partials

  const int t    = threadIdx.x;
  const int b    = blockIdx.x;
  const int lane = t & 63;
  const int wv   = __builtin_amdgcn_readfirstlane(t >> 6);
  const int r    = lane & 15;
  const int q    = lane >> 4;

  // ---------- P0: embeddings + alias/mask; hoisted A-fragments ----------
  {
    const int* itb = items + b * NN;
    for (int j = t; j < NN * HH; j += BDIM) {
      int n = j >> 7, k = j & 127;
      sH[n * SH_STR + k] = f2b(emb[(size_t)itb[n] * HH + k]);
    }
    if (t < 64) {
      sAliasRow[t] = alias_input[b * 64 + t];
      sMaskArr[t]  = mask[b * 64 + t];
    }
  }

  // A-fragments: step-invariant, load+pack once (wave's half of A)
  v8s a2[4][2];
  {
    const int half = wv >> 1;
    #pragma unroll
    for (int mt = 0; mt < 4; ++mt)
      #pragma unroll
      for (int kk = 0; kk < 2; ++kk)
        a2[mt][kk] = pack8(A + (size_t)(b * NN + mt * 16 + r) * (2 * NN)
                             + half * 64 + kk * 32 + q * 8);
  }
  __syncthreads();

  for (int step = 0; step < 2; ++step) {
    // ---------- P1 (MFMA): sX[n][c] = bias[c] + sum_k H[n][k]*W[c][k] ----------
    {
      v8s a[4][4];
      #pragma unroll
      for (int mt = 0; mt < 4; ++mt)
        #pragma unroll
        for (int kk = 0; kk < 4; ++kk)
          a[mt][kk] = ldsA(sH, SH_STR, mt * 16, kk * 32, r, q);

      const int    wbase = (wv < 2) ? OFS_WIN : OFS_WOUT;
      const float* bsel  = (wv < 2) ? b_in : b_out;
      const int    ntofs = (wv < 2) ? 0 : 8;
      #pragma unroll 2
      for (int i = 0; i < 4; ++i) {
        int nt = wv * 4 + i;
        int tr = nt - ntofs;
        int c  = nt * 16 + r;
        float bini = bsel[tr * 16 + r];
        v4f acc0 = {bini, bini, bini, bini}, acc1 = acc0, acc2 = acc0, acc3 = acc0;
        #pragma unroll
        for (int kk = 0; kk < 4; ++kk) {
          v8s bf = ldfrag(ws, wbase, tr * 4 + kk, lane);
          acc0 = MFMA(a[0][kk], bf, acc0);
          acc1 = MFMA(a[1][kk], bf, acc1);
          acc2 = MFMA(a[2][kk], bf, acc2);
          acc3 = MFMA(a[3][kk], bf, acc3);
        }
        #pragma unroll
        for (int reg = 0; reg < 4; ++reg) {
          sX[(0  + q * 4 + reg) * SX_STR + c] = f2b(acc0[reg]);
          sX[(16 + q * 4 + reg) * SX_STR + c] = f2b(acc1[reg]);
          sX[(32 + q * 4 + reg) * SX_STR + c] = f2b(acc2[reg]);
          sX[(48 + q * 4 + reg) * SX_STR + c] = f2b(acc3[reg]);
        }
      }
    }
    // no barrier: each wave reads back only its own columns in P2

    // ---------- P2 (MFMA): ie[n][c] = bias[c] + sum_m Adj[n][m]*X[m][c] ----
    {
      const float* bsel2 = (wv < 2) ? b_iah : b_oah;
      const int    wofs2 = (wv < 2) ? 0 : 128;
      #pragma unroll 1
      for (int i = 0; i < 4; ++i) {
        int nt = wv * 4 + i;
        int c  = nt * 16 + r;
        v8s b0, b1f;
        #pragma unroll
        for (int j = 0; j < 8; ++j) {
          b0[j]  = (short)sX[(q * 8 + j) * SX_STR + c];
          b1f[j] = (short)sX[(32 + q * 8 + j) * SX_STR + c];
        }
        float bini = bsel2[c - wofs2];
        v4f acc0 = {bini, bini, bini, bini}, acc1 = acc0, acc2 = acc0, acc3 = acc0;
        acc0 = MFMA(a2[0][0], b0, acc0); acc0 = MFMA(a2[0][1], b1f, acc0);
        acc1 = MFMA(a2[1][0], b0, acc1); acc1 = MFMA(a2[1][1], b1f, acc1);
        acc2 = MFMA(a2[2][0], b0, acc2); acc2 = MFMA(a2[2][1], b1f, acc2);
        acc3 = MFMA(a2[3][0], b0, acc3); acc3 = MFMA(a2[3][1], b1f, acc3);
        #pragma unroll
        for (int reg = 0; reg < 4; ++reg) {
          sX[(0  + q * 4 + reg) * SX_STR + c] = f2b(acc0[reg]);
          sX[(16 + q * 4 + reg) * SX_STR + c] = f2b(acc1[reg]);
          sX[(32 + q * 4 + reg) * SX_STR + c] = f2b(acc2[reg]);
          sX[(48 + q * 4 + reg) * SX_STR + c] = f2b(acc3[reg]);
        }
      }
    }

    // prefetch gi kk=0 B-frags for both u (latency overlaps the barrier)
    v8s pR[2], pI[2], pN[2];
    #pragma unroll
    for (int u = 0; u < 2; ++u) {
      int trb = wv * 2 + u;
      pR[u] = ldfrag(ws, OFS_WI, (0  + trb) * 8, lane);
      pI[u] = ldfrag(ws, OFS_WI, (8  + trb) * 8, lane);
      pN[u] = ldfrag(ws, OFS_WI, (16 + trb) * 8, lane);
    }
    __syncthreads();   // P3 reads all columns of sX / rows of sH

    // ---------- P3 (MFMA): gates, two u-passes; gi+gh interleaved ----------
    {
      const int h0 = wv * 32;
      uint32_t nhpk[2][8];

      #pragma unroll 1
      for (int u = 0; u < 2; ++u) {
        int h = h0 + u * 16 + r;
        float vR  = bi[h] + bh[h];
        float vI  = bi[128 + h] + bh[128 + h];
        float vNi = bi[256 + h];
        float vNh = bh[256 + h];
        v4f aR[4], aI[4], aNi[4], aNh[4];
        #pragma unroll
        for (int mt = 0; mt < 4; ++mt) {
          aR[mt]  = (v4f){vR, vR, vR, vR};
          aI[mt]  = (v4f){vI, vI, vI, vI};
          aNi[mt] = (v4f){vNi, vNi, vNi, vNi};
          aNh[mt] = (v4f){vNh, vNh, vNh, vNh};
        }
        const int trb = wv * 2 + u;

        // kk = 0..3: gi (kk) + gh (kk) interleaved; kk=0 gi frags prefetched
        #pragma unroll 1
        for (int kk = 0; kk < 4; ++kk) {
          v8s bR = (kk == 0) ? pR[u] : ldfrag(ws, OFS_WI, (0  + trb) * 8 + kk, lane);
          v8s bI = (kk == 0) ? pI[u] : ldfrag(ws, OFS_WI, (8  + trb) * 8 + kk, lane);
          v8s bN = (kk == 0) ? pN[u] : ldfrag(ws, OFS_WI, (16 + trb) * 8 + kk, lane);
          v8s cR = ldfrag(ws, OFS_WH, (0  + trb) * 4 + kk, lane);
          v8s cI = ldfrag(ws, OFS_WH, (8  + trb) * 4 + kk, lane);
          v8s cN = ldfrag(ws, OFS_WH, (16 + trb) * 4 + kk, lane);
          v8s af0 = ldsA(sX, SX_STR, 0,  kk * 32, r, q);
          v8s af1 = ldsA(sX, SX_STR, 16, kk * 32, r, q);
          v8s af2 = ldsA(sX, SX_STR, 32, kk * 32, r, q);
          v8s af3 = ldsA(sX, SX_STR, 48, kk * 32, r, q);
          v8s ag0 = ldsA(sH, SH_STR, 0,  kk * 32, r, q);
          v8s ag1 = ldsA(sH, SH_STR, 16, kk * 32, r, q);
          v8s ag2 = ldsA(sH, SH_STR, 32, kk * 32, r, q);
          v8s ag3 = ldsA(sH, SH_STR, 48, kk * 32, r, q);
          aR[0]  = MFMA(af0, bR, aR[0]);  aR[1]  = MFMA(af1, bR, aR[1]);
          aR[2]  = MFMA(af2, bR, aR[2]);  aR[3]  = MFMA(af3, bR, aR[3]);
          aI[0]  = MFMA(af0, bI, aI[0]);  aI[1]  = MFMA(af1, bI, aI[1]);
          aI[2]  = MFMA(af2, bI, aI[2]);  aI[3]  = MFMA(af3, bI, aI[3]);
          aNi[0] = MFMA(af0, bN, aNi[0]); aNi[1] = MFMA(af1, bN, aNi[1]);
          aNi[2] = MFMA(af2, bN, aNi[2]); aNi[3] = MFMA(af3, bN, aNi[3]);
          aR[0]  = MFMA(ag0, cR, aR[0]);  aR[1]  = MFMA(ag1, cR, aR[1]);
          aR[2]  = MFMA(ag2, cR, aR[2]);  aR[3]  = MFMA(ag3, cR, aR[3]);
          aI[0]  = MFMA(ag0, cI, aI[0]);  aI[1]  = MFMA(ag1, cI, aI[1]);
          aI[2]  = MFMA(ag2, cI, aI[2]);  aI[3]  = MFMA(ag3, cI, aI[3]);
          aNh[0] = MFMA(ag0, cN, aNh[0]); aNh[1] = MFMA(ag1, cN, aNh[1]);
          aNh[2] = MFMA(ag2, cN, aNh[2]); aNh[3] = MFMA(ag3, cN, aNh[3]);
        }
        // kk = 4..7: gi only
        #pragma unroll 2
        for (int kk = 4; kk < 8; ++kk) {
          v8s bR = ldfrag(ws, OFS_WI, (0  + trb) * 8 + kk, lane);
          v8s bI = ldfrag(ws, OFS_WI, (8  + trb) * 8 + kk, lane);
          v8s bN = ldfrag(ws, OFS_WI, (16 + trb) * 8 + kk, lane);
          v8s af0 = ldsA(sX, SX_STR, 0,  kk * 32, r, q);
          v8s af1 = ldsA(sX, SX_STR, 16, kk * 32, r, q);
          v8s af2 = ldsA(sX, SX_STR, 32, kk * 32, r, q);
          v8s af3 = ldsA(sX, SX_STR, 48, kk * 32, r, q);
          aR[0]  = MFMA(af0, bR, aR[0]);  aR[1]  = MFMA(af1, bR, aR[1]);
          aR[2]  = MFMA(af2, bR, aR[2]);  aR[3]  = MFMA(af3, bR, aR[3]);
          aI[0]  = MFMA(af0, bI, aI[0]);  aI[1]  = MFMA(af1, bI, aI[1]);
          aI[2]  = MFMA(af2, bI, aI[2]);  aI[3]  = MFMA(af3, bI, aI[3]);
          aNi[0] = MFMA(af0, bN, aNi[0]); aNi[1] = MFMA(af1, bN, aNi[1]);
          aNi[2] = MFMA(af2, bN, aNi[2]); aNi[3] = MFMA(af3, bN, aNi[3]);
        }
        // epilogue-compute: stash new hidden as packed bf16
        #pragma unroll
        for (int mt = 0; mt < 4; ++mt) {
          #pragma unroll
          for (int rp = 0; rp < 2; ++rp) {
            uint32_t pk = 0;
            #pragma unroll
            for (int e = 0; e < 2; ++e) {
              int reg = rp * 2 + e;
              int row = mt * 16 + q * 4 + reg;
              float z  = sig_f(aI[mt][reg]);
              float rr = sig_f(aR[mt][reg]);
              float gg = tanh_f(fmaf(rr, aNh[mt][reg], aNi[mt][reg]));
              float hp = b2f(sH[row * SH_STR + h]);
              pk |= (uint32_t)f2b(fmaf(z, gg - hp, hp)) << (16 * e);
            }
            nhpk[u][mt * 2 + rp] = pk;
          }
        }
      }
      __syncthreads();   // all waves done reading sX/sH before sH overwrite

      #pragma unroll
      for (int u = 0; u < 2; ++u) {
        int h = h0 + u * 16 + r;
        #pragma unroll
        for (int mt = 0; mt < 4; ++mt)
          #pragma unroll
          for (int rp = 0; rp < 2; ++rp) {
            uint32_t pk = nhpk[u][mt * 2 + rp];
            int row = mt * 16 + q * 4 + rp * 2;
            sH[row * SH_STR + h]       = (uint16_t)(pk & 0xffff);
            sH[(row + 1) * SH_STR + h] = (uint16_t)(pk >> 16);
          }
      }
    }
    __syncthreads();
  }

  // ---------- P4: attention readout (half-split dots; scratch in sX) ----------
  int msum = 0;
  #pragma unroll
  for (int l = 0; l < 64; ++l) msum += sMaskArr[l];
  const int lastRow = sAliasRow[msum - 1];
  const int hh  = t & 127;
  const int seg = t >> 7;

  // q1 partials: seg covers elems [seg*64, seg*64+64)
  {
    const float4* w14 = reinterpret_cast<const float4*>(w1 + (size_t)hh * HH + seg * 64);
    const uint2*  lr  = reinterpret_cast<const uint2*>(&sH[lastRow * SH_STR + seg * 64]);
    float a0 = seg ? 0.f : b1[hh], a1 = 0.f, a2v = 0.f, a3 = 0.f;
    #pragma unroll 8
    for (int j = 0; j < 16; ++j) {
      float4 w = w14[j]; uint2 v = lr[j];
      a0  = fmaf(b2f_lo(v.x), w.x, a0);  a1 = fmaf(b2f_hi(v.x), w.y, a1);
      a2v = fmaf(b2f_lo(v.y), w.z, a2v); a3 = fmaf(b2f_hi(v.y), w.w, a3);
    }
    sP[seg * 128 + hh] = (a0 + a1) + (a2v + a3);
  }
  __syncthreads();
  if (t < HH) sQ1v[t] = sP[t] + sP[128 + t];
  __syncthreads();

  // alpha (MFMA): wave wv covers h in [wv*32, wv*32+32)
  {
    v8s a[4][4];
    #pragma unroll
    for (int mt = 0; mt < 4; ++mt) {
      int row = sAliasRow[mt * 16 + r];
      #pragma unroll
      for (int kk = 0; kk < 4; ++kk)
        a[mt][kk] = *reinterpret_cast<const v8s*>(&sH[row * SH_STR + kk * 32 + q * 8]);
    }
    float part[16];
    #pragma unroll
    for (int i = 0; i < 16; ++i) part[i] = 0.f;
    #pragma unroll
    for (int u = 0; u < 2; ++u) {
      int h = wv * 32 + u * 16 + r;
      float binit = sQ1v[h] + b2[h];
      v4f acc[4];
      #pragma unroll
      for (int mt = 0; mt < 4; ++mt) acc[mt] = (v4f){binit, binit, binit, binit};
      #pragma unroll
      for (int kk = 0; kk < 4; ++kk) {
        v8s bf = ldfrag(ws, OFS_W2, (wv * 2 + u) * 4 + kk, lane);
        acc[0] = MFMA(a[0][kk], bf, acc[0]);
        acc[1] = MFMA(a[1][kk], bf, acc[1]);
        acc[2] = MFMA(a[2][kk], bf, acc[2]);
        acc[3] = MFMA(a[3][kk], bf, acc[3]);
      }
      float wqh = wq[h];
      #pragma unroll
      for (int mt = 0; mt < 4; ++mt)
        #pragma unroll
        for (int reg = 0; reg < 4; ++reg)
          part[mt * 4 + reg] += sig_f(acc[mt][reg]) * wqh;
    }
    #pragma unroll
    for (int m = 1; m <= 8; m <<= 1)
      #pragma unroll
      for (int i = 0; i < 16; ++i)
        part[i] += __shfl_xor(part[i], m);
    if (r == 0) {
      #pragma unroll
      for (int mt = 0; mt < 4; ++mt)
        #pragma unroll
        for (int reg = 0; reg < 4; ++reg)
          sAPartv[wv * 64 + mt * 16 + q * 4 + reg] = part[mt * 4 + reg];
    }
  }
  __syncthreads();
  if (t < 64) {
    sAlphav[t] = (sAPartv[t] + sAPartv[64 + t] + sAPartv[128 + t] + sAPartv[192 + t])
               * (float)sMaskArr[t];
  }
  __syncthreads();

  // glob partials: seg covers l in [seg*32, seg*32+32)
  {
    float acc = 0.0f;
    #pragma unroll
    for (int l = 0; l < 32; ++l) {
      int ll = seg * 32 + l;
      acc = fmaf(sAlphav[ll], b2f(sH[sAliasRow[ll] * SH_STR + hh]), acc);
    }
    sP[seg * 128 + hh] = acc;
  }
  __syncthreads();
  if (t < HH) sGlobv[t] = sP[t] + sP[128 + t];
  __syncthreads();

  // w3: seg 0 -> local part, seg 1 -> glob part
  {
    const float4* w34 = reinterpret_cast<const float4*>(w3 + (size_t)hh * 256 + seg * 128);
    float a0 = seg ? 0.f : b3[hh], a1 = 0.f, a2v = 0.f, a3 = 0.f;
    if (seg == 0) {
      const uint2* lr = reinterpret_cast<const uint2*>(&sH[lastRow * SH_STR]);
      #pragma unroll 8
      for (int j = 0; j < 32; ++j) {
        float4 w = w34[j]; uint2 v = lr[j];
        a0  = fmaf(b2f_lo(v.x), w.x, a0);  a1 = fmaf(b2f_hi(v.x), w.y, a1);
        a2v = fmaf(b2f_lo(v.y), w.z, a2v); a3 = fmaf(b2f_hi(v.y), w.w, a3);
      }
    } else {
      #pragma unroll 8
      for (int j = 0; j < 32; ++j) {
        float4 w = w34[j];
        a0  = fmaf(sGlobv[4*j+0], w.x, a0);  a1 = fmaf(sGlobv[4*j+1], w.y, a1);
        a2v = fmaf(sGlobv[4*j+2], w.z, a2v); a3 = fmaf(sGlobv[4*j+3], w.w, a3);
      }
    }
    sP[seg * 128 + hh] = (a0 + a1) + (a2v + a3);
  }
  __syncthreads();
  if (t < HH) out[b * HH + t] = sP[t] + sP[128 + t];
}

extern "C" void kernel_launch(void* const* d_in, const int* in_sizes, int n_in,
                              void* d_out, int out_size, void* d_ws, size_t ws_size,
                              hipStream_t stream) {
  const float* A          = (const float*)d_in[0];
  const int*   items      = (const int*)  d_in[1];
  const int*   mask       = (const int*)  d_in[2];
  const int*   alias_in   = (const int*)  d_in[3];
  const float* emb        = (const float*)d_in[4];
  const float* w_in       = (const float*)d_in[5];
  const float* b_in       = (const float*)d_in[6];
  const float* w_out      = (const float*)d_in[7];
  const float* b_out      = (const float*)d_in[8];
  const float* b_iah      = (const float*)d_in[9];
  const float* b_oah      = (const float*)d_in[10];
  const float* wi         = (const float*)d_in[11];
  const float* bi         = (const float*)d_in[12];
  const float* wh         = (const float*)d_in[13];
  const float* bh         = (const float*)d_in[14];
  const float* w1         = (const float*)d_in[15];
  const float* b1         = (const float*)d_in[16];
  const float* w2         = (const float*)d_in[17];
  const float* b2         = (const float*)d_in[18];
  const float* wq         = (const float*)d_in[19];
  const float* w3         = (const float*)d_in[20];
  const float* b3         = (const float*)d_in[21];
  float* out = (float*)d_out;
  uint16_t* wsp = (uint16_t*)d_ws;

  hipLaunchKernelGGL(pack_weights, dim3((N_FRAGS + 255) / 256), dim3(256), 0, stream,
                     w_in, w_out, wi, wh, w2, wsp);
  hipLaunchKernelGGL(srgnn_kernel, dim3(NB), dim3(BDIM), 0, stream,
                     A, items, mask, alias_in, emb,
                     b_in, b_out, b_iah, b_oah, bi, bh,
                     w1, b1, b2, wq, w3, b3, wsp, out);
}

// Round 10
// 255.283 us; speedup vs baseline: 1.1173x; 1.1173x over previous
//
#include <hip/hip_runtime.h>
#include <stdint.h>

// SR-GNN fused, R10: R8's P3 restored (separate gi/gh loops, unroll 2 —
// R9's interleave doubled HBM fetch + broke iteration pipelining, -20%).
// Kept from R9: P4 half-split dots (seg = t>>7) + P4 scratch aliased into sX.

#define BDIM 256
#define NB   1024
#define NN   64
#define HH   128
#define SH_STR 136   // u16 stride; 272B rows
#define SX_STR 264   // u16 stride; 528B rows

// d_ws fragment-layout offsets (u16 units)
#define OFS_WIN  0         // w_in : 8 tr x 4 kc x 64 lanes x 8  = 16384
#define OFS_WOUT 16384     // w_out: 16384
#define OFS_WI   32768     // wi   : 24 tr x 8 kc x 64 x 8       = 98304
#define OFS_WH   131072    // wh   : 24 tr x 4 kc x 64 x 8       = 49152
#define OFS_W2   180224    // w2   : 8 tr x 4 kc x 64 x 8        = 16384
#define N_FRAGS  24576     // total frags (16B each) = 384 KB

typedef short v8s __attribute__((ext_vector_type(8)));
typedef float v4f __attribute__((ext_vector_type(4)));

__device__ __forceinline__ float b2f_lo(uint32_t u){
  union { uint32_t u; float f; } v; v.u = u << 16; return v.f;
}
__device__ __forceinline__ float b2f_hi(uint32_t u){
  union { uint32_t u; float f; } v; v.u = u & 0xffff0000u; return v.f;
}
__device__ __forceinline__ uint16_t f2b(float f){   // RNE
  union { float f; uint32_t u; } v; v.f = f;
  uint32_t r = v.u + 0x7fffu + ((v.u >> 16) & 1u);
  return (uint16_t)(r >> 16);
}
__device__ __forceinline__ float b2f(uint16_t s){
  union { uint32_t u; float f; } v; v.u = ((uint32_t)s) << 16; return v.f;
}
__device__ __forceinline__ float sig_f(float x){ return 1.0f / (1.0f + __expf(-x)); }
__device__ __forceinline__ float tanh_f(float x){ return 1.0f - 2.0f / (__expf(2.0f*x) + 1.0f); }

__device__ __forceinline__ uint32_t pack2bf(float a, float b){
  union { float f; uint32_t u; } ua, ub; ua.f = a; ub.f = b;
  return __builtin_amdgcn_perm(ub.u + 0x8000u, ua.u + 0x8000u, 0x07060302u);
}

__device__ __forceinline__ v8s pack8(const float* __restrict__ p){
  float4 f0 = *reinterpret_cast<const float4*>(p);
  float4 f1 = *reinterpret_cast<const float4*>(p + 4);
  union { uint32_t u[4]; v8s v; } o;
  o.u[0] = pack2bf(f0.x, f0.y);
  o.u[1] = pack2bf(f0.z, f0.w);
  o.u[2] = pack2bf(f1.x, f1.y);
  o.u[3] = pack2bf(f1.z, f1.w);
  return o.v;
}

__device__ __forceinline__ v8s ldsA(const uint16_t* buf, int stride,
                                    int row_base, int k_base, int r, int q){
  return *reinterpret_cast<const v8s*>(&buf[(row_base + r) * stride + k_base + q * 8]);
}

__device__ __forceinline__ v8s ldfrag(const uint16_t* __restrict__ ws,
                                      int base, int tile, int lane){
  return *reinterpret_cast<const v8s*>(ws + base + (((size_t)tile * 64 + lane) << 3));
}

#define MFMA(a, b, c) __builtin_amdgcn_mfma_f32_16x16x32_bf16((a), (b), (c), 0, 0, 0)

// ---------------- pre-pass: pack weights into frag layout ----------------
__global__ __launch_bounds__(256) void pack_weights(
    const float* __restrict__ w_in, const float* __restrict__ w_out,
    const float* __restrict__ wi,   const float* __restrict__ wh,
    const float* __restrict__ w2,   uint16_t* __restrict__ ws)
{
  int gid = blockIdx.x * blockDim.x + threadIdx.x;
  if (gid >= N_FRAGS) return;
  const float* W; int C; int fi; int base;
  if (gid < 2048)       { W = w_in;  C = 128; fi = gid;         base = OFS_WIN; }
  else if (gid < 4096)  { W = w_out; C = 128; fi = gid - 2048;  base = OFS_WOUT; }
  else if (gid < 16384) { W = wi;    C = 256; fi = gid - 4096;  base = OFS_WI; }
  else if (gid < 22528) { W = wh;    C = 128; fi = gid - 16384; base = OFS_WH; }
  else                  { W = w2;    C = 128; fi = gid - 22528; base = OFS_W2; }
  int lane = fi & 63;
  int tile = fi >> 6;
  int tc   = C >> 5;
  int tr   = tile / tc, kc = tile - tr * tc;
  int r = lane & 15, q = lane >> 4;
  const float* p = W + (size_t)(tr * 16 + r) * C + kc * 32 + q * 8;
  *reinterpret_cast<v8s*>(ws + base + ((size_t)fi << 3)) = pack8(p);
}

// ---------------- main kernel ----------------
__global__ __launch_bounds__(BDIM, 3) void srgnn_kernel(
    const float* __restrict__ A,
    const int*   __restrict__ items,
    const int*   __restrict__ mask,
    const int*   __restrict__ alias_input,
    const float* __restrict__ emb,
    const float* __restrict__ b_in,  const float* __restrict__ b_out,
    const float* __restrict__ b_iah, const float* __restrict__ b_oah,
    const float* __restrict__ bi,    const float* __restrict__ bh,
    const float* __restrict__ w1,    const float* __restrict__ b1,
    const float* __restrict__ b2,
    const float* __restrict__ wq,
    const float* __restrict__ w3,    const float* __restrict__ b3,
    const uint16_t* __restrict__ ws,
    float* __restrict__ out)
{
  __shared__ __align__(16) uint16_t sH[NN * SH_STR];   // hidden bf16, 17.0 KB
  __shared__ __align__(16) uint16_t sX[NN * SX_STR];   // ie bf16 / P4 scratch, 33.0 KB
  __shared__ int sAliasRow[64], sMaskArr[64];

  // P4 float scratch aliased into sX (dead after last P3)
  float* sF      = reinterpret_cast<float*>(sX);
  float* sQ1v    = sF;          // 128
  float* sGlobv  = sF + 128;    // 128
  float* sAPartv = sF + 256;    // 4*64
  float* sAlphav = sF + 512;    // 64
  float* sP      = sF + 576;    // 2*128 partials

  const int t    = threadIdx.x;
  const int b    = blockIdx.x;
  const int lane = t & 63;
  const int wv   = __builtin_amdgcn_readfirstlane(t >> 6);
  const int r    = lane & 15;
  const int q    = lane >> 4;

  // ---------- P0: embeddings + alias/mask; hoisted A-fragments ----------
  {
    const int* itb = items + b * NN;
    for (int j = t; j < NN * HH; j += BDIM) {
      int n = j >> 7, k = j & 127;
      sH[n * SH_STR + k] = f2b(emb[(size_t)itb[n] * HH + k]);
    }
    if (t < 64) {
      sAliasRow[t] = alias_input[b * 64 + t];
      sMaskArr[t]  = mask[b * 64 + t];
    }
  }

  // A-fragments: step-invariant, load+pack once (wave's half of A)
  v8s a2[4][2];
  {
    const int half = wv >> 1;
    #pragma unroll
    for (int mt = 0; mt < 4; ++mt)
      #pragma unroll
      for (int kk = 0; kk < 2; ++kk)
        a2[mt][kk] = pack8(A + (size_t)(b * NN + mt * 16 + r) * (2 * NN)
                             + half * 64 + kk * 32 + q * 8);
  }
  __syncthreads();

  for (int step = 0; step < 2; ++step) {
    // ---------- P1 (MFMA): sX[n][c] = bias[c] + sum_k H[n][k]*W[c][k] ----------
    {
      v8s a[4][4];
      #pragma unroll
      for (int mt = 0; mt < 4; ++mt)
        #pragma unroll
        for (int kk = 0; kk < 4; ++kk)
          a[mt][kk] = ldsA(sH, SH_STR, mt * 16, kk * 32, r, q);

      const int    wbase = (wv < 2) ? OFS_WIN : OFS_WOUT;
      const float* bsel  = (wv < 2) ? b_in : b_out;
      const int    ntofs = (wv < 2) ? 0 : 8;
      #pragma unroll 2
      for (int i = 0; i < 4; ++i) {
        int nt = wv * 4 + i;
        int tr = nt - ntofs;
        int c  = nt * 16 + r;
        float bini = bsel[tr * 16 + r];
        v4f acc0 = {bini, bini, bini, bini}, acc1 = acc0, acc2 = acc0, acc3 = acc0;
        #pragma unroll
        for (int kk = 0; kk < 4; ++kk) {
          v8s bf = ldfrag(ws, wbase, tr * 4 + kk, lane);
          acc0 = MFMA(a[0][kk], bf, acc0);
          acc1 = MFMA(a[1][kk], bf, acc1);
          acc2 = MFMA(a[2][kk], bf, acc2);
          acc3 = MFMA(a[3][kk], bf, acc3);
        }
        #pragma unroll
        for (int reg = 0; reg < 4; ++reg) {
          sX[(0  + q * 4 + reg) * SX_STR + c] = f2b(acc0[reg]);
          sX[(16 + q * 4 + reg) * SX_STR + c] = f2b(acc1[reg]);
          sX[(32 + q * 4 + reg) * SX_STR + c] = f2b(acc2[reg]);
          sX[(48 + q * 4 + reg) * SX_STR + c] = f2b(acc3[reg]);
        }
      }
    }
    // no barrier: each wave reads back only its own columns in P2

    // ---------- P2 (MFMA): ie[n][c] = bias[c] + sum_m Adj[n][m]*X[m][c] ----
    {
      const float* bsel2 = (wv < 2) ? b_iah : b_oah;
      const int    wofs2 = (wv < 2) ? 0 : 128;
      #pragma unroll 1
      for (int i = 0; i < 4; ++i) {
        int nt = wv * 4 + i;
        int c  = nt * 16 + r;
        v8s b0, b1f;
        #pragma unroll
        for (int j = 0; j < 8; ++j) {
          b0[j]  = (short)sX[(q * 8 + j) * SX_STR + c];
          b1f[j] = (short)sX[(32 + q * 8 + j) * SX_STR + c];
        }
        float bini = bsel2[c - wofs2];
        v4f acc0 = {bini, bini, bini, bini}, acc1 = acc0, acc2 = acc0, acc3 = acc0;
        acc0 = MFMA(a2[0][0], b0, acc0); acc0 = MFMA(a2[0][1], b1f, acc0);
        acc1 = MFMA(a2[1][0], b0, acc1); acc1 = MFMA(a2[1][1], b1f, acc1);
        acc2 = MFMA(a2[2][0], b0, acc2); acc2 = MFMA(a2[2][1], b1f, acc2);
        acc3 = MFMA(a2[3][0], b0, acc3); acc3 = MFMA(a2[3][1], b1f, acc3);
        #pragma unroll
        for (int reg = 0; reg < 4; ++reg) {
          sX[(0  + q * 4 + reg) * SX_STR + c] = f2b(acc0[reg]);
          sX[(16 + q * 4 + reg) * SX_STR + c] = f2b(acc1[reg]);
          sX[(32 + q * 4 + reg) * SX_STR + c] = f2b(acc2[reg]);
          sX[(48 + q * 4 + reg) * SX_STR + c] = f2b(acc3[reg]);
        }
      }
    }
    __syncthreads();

    // ---------- P3 (MFMA): gates, two u-passes of 16 h-cols (R8 schedule) ----
    {
      const int h0 = wv * 32;
      uint32_t nhpk[2][8];

      #pragma unroll 1
      for (int u = 0; u < 2; ++u) {
        int h = h0 + u * 16 + r;
        float vR  = bi[h] + bh[h];
        float vI  = bi[128 + h] + bh[128 + h];
        float vNi = bi[256 + h];
        float vNh = bh[256 + h];
        v4f aR[4], aI[4], aNi[4], aNh[4];
        #pragma unroll
        for (int mt = 0; mt < 4; ++mt) {
          aR[mt]  = (v4f){vR, vR, vR, vR};
          aI[mt]  = (v4f){vI, vI, vI, vI};
          aNi[mt] = (v4f){vNi, vNi, vNi, vNi};
          aNh[mt] = (v4f){vNh, vNh, vNh, vNh};
        }
        const int trb = wv * 2 + u;
        // gi: IE[64x256] @ wi^T
        #pragma unroll 2
        for (int kk = 0; kk < 8; ++kk) {
          v8s af0 = ldsA(sX, SX_STR, 0,  kk * 32, r, q);
          v8s af1 = ldsA(sX, SX_STR, 16, kk * 32, r, q);
          v8s af2 = ldsA(sX, SX_STR, 32, kk * 32, r, q);
          v8s af3 = ldsA(sX, SX_STR, 48, kk * 32, r, q);
          v8s bR = ldfrag(ws, OFS_WI, (0 * 8 + trb) * 8 + kk, lane);
          v8s bI = ldfrag(ws, OFS_WI, (8 + trb) * 8 + kk, lane);
          v8s bN = ldfrag(ws, OFS_WI, (16 + trb) * 8 + kk, lane);
          aR[0]  = MFMA(af0, bR, aR[0]);  aR[1]  = MFMA(af1, bR, aR[1]);
          aR[2]  = MFMA(af2, bR, aR[2]);  aR[3]  = MFMA(af3, bR, aR[3]);
          aI[0]  = MFMA(af0, bI, aI[0]);  aI[1]  = MFMA(af1, bI, aI[1]);
          aI[2]  = MFMA(af2, bI, aI[2]);  aI[3]  = MFMA(af3, bI, aI[3]);
          aNi[0] = MFMA(af0, bN, aNi[0]); aNi[1] = MFMA(af1, bN, aNi[1]);
          aNi[2] = MFMA(af2, bN, aNi[2]); aNi[3] = MFMA(af3, bN, aNi[3]);
        }
        // gh: H[64x128] @ wh^T
        #pragma unroll 2
        for (int kk = 0; kk < 4; ++kk) {
          v8s af0 = ldsA(sH, SH_STR, 0,  kk * 32, r, q);
          v8s af1 = ldsA(sH, SH_STR, 16, kk * 32, r, q);
          v8s af2 = ldsA(sH, SH_STR, 32, kk * 32, r, q);
          v8s af3 = ldsA(sH, SH_STR, 48, kk * 32, r, q);
          v8s bR = ldfrag(ws, OFS_WH, (0 * 8 + trb) * 4 + kk, lane);
          v8s bI = ldfrag(ws, OFS_WH, (8 + trb) * 4 + kk, lane);
          v8s bN = ldfrag(ws, OFS_WH, (16 + trb) * 4 + kk, lane);
          aR[0]  = MFMA(af0, bR, aR[0]);  aR[1]  = MFMA(af1, bR, aR[1]);
          aR[2]  = MFMA(af2, bR, aR[2]);  aR[3]  = MFMA(af3, bR, aR[3]);
          aI[0]  = MFMA(af0, bI, aI[0]);  aI[1]  = MFMA(af1, bI, aI[1]);
          aI[2]  = MFMA(af2, bI, aI[2]);  aI[3]  = MFMA(af3, bI, aI[3]);
          aNh[0] = MFMA(af0, bN, aNh[0]); aNh[1] = MFMA(af1, bN, aNh[1]);
          aNh[2] = MFMA(af2, bN, aNh[2]); aNh[3] = MFMA(af3, bN, aNh[3]);
        }
        // epilogue-compute: stash new hidden as packed bf16 (no LDS write yet)
        #pragma unroll
        for (int mt = 0; mt < 4; ++mt) {
          #pragma unroll
          for (int rp = 0; rp < 2; ++rp) {
            uint32_t pk = 0;
            #pragma unroll
            for (int e = 0; e < 2; ++e) {
              int reg = rp * 2 + e;
              int row = mt * 16 + q * 4 + reg;
              float z  = sig_f(aI[mt][reg]);
              float rr = sig_f(aR[mt][reg]);
              float gg = tanh_f(fmaf(rr, aNh[mt][reg], aNi[mt][reg]));
              float hp = b2f(sH[row * SH_STR + h]);
              pk |= (uint32_t)f2b(fmaf(z, gg - hp, hp)) << (16 * e);
            }
            nhpk[u][mt * 2 + rp] = pk;
          }
        }
      }
      __syncthreads();   // all waves done reading sX/sH before sH overwrite

      #pragma unroll
      for (int u = 0; u < 2; ++u) {
        int h = h0 + u * 16 + r;
        #pragma unroll
        for (int mt = 0; mt < 4; ++mt)
          #pragma unroll
          for (int rp = 0; rp < 2; ++rp) {
            uint32_t pk = nhpk[u][mt * 2 + rp];
            int row = mt * 16 + q * 4 + rp * 2;
            sH[row * SH_STR + h]       = (uint16_t)(pk & 0xffff);
            sH[(row + 1) * SH_STR + h] = (uint16_t)(pk >> 16);
          }
      }
    }
    __syncthreads();
  }

  // ---------- P4: attention readout (half-split dots; scratch in sX) ----------
  int msum = 0;
  #pragma unroll
  for (int l = 0; l < 64; ++l) msum += sMaskArr[l];
  const int lastRow = sAliasRow[msum - 1];
  const int hh  = t & 127;
  const int seg = t >> 7;

  // q1 partials: seg covers elems [seg*64, seg*64+64)
  {
    const float4* w14 = reinterpret_cast<const float4*>(w1 + (size_t)hh * HH + seg * 64);
    const uint2*  lr  = reinterpret_cast<const uint2*>(&sH[lastRow * SH_STR + seg * 64]);
    float a0 = seg ? 0.f : b1[hh], a1 = 0.f, a2v = 0.f, a3 = 0.f;
    #pragma unroll 8
    for (int j = 0; j < 16; ++j) {
      float4 w = w14[j]; uint2 v = lr[j];
      a0  = fmaf(b2f_lo(v.x), w.x, a0);  a1 = fmaf(b2f_hi(v.x), w.y, a1);
      a2v = fmaf(b2f_lo(v.y), w.z, a2v); a3 = fmaf(b2f_hi(v.y), w.w, a3);
    }
    sP[seg * 128 + hh] = (a0 + a1) + (a2v + a3);
  }
  __syncthreads();
  if (t < HH) sQ1v[t] = sP[t] + sP[128 + t];
  __syncthreads();

  // alpha (MFMA): wave wv covers h in [wv*32, wv*32+32)
  {
    v8s a[4][4];
    #pragma unroll
    for (int mt = 0; mt < 4; ++mt) {
      int row = sAliasRow[mt * 16 + r];
      #pragma unroll
      for (int kk = 0; kk < 4; ++kk)
        a[mt][kk] = *reinterpret_cast<const v8s*>(&sH[row * SH_STR + kk * 32 + q * 8]);
    }
    float part[16];
    #pragma unroll
    for (int i = 0; i < 16; ++i) part[i] = 0.f;
    #pragma unroll
    for (int u = 0; u < 2; ++u) {
      int h = wv * 32 + u * 16 + r;
      float binit = sQ1v[h] + b2[h];
      v4f acc[4];
      #pragma unroll
      for (int mt = 0; mt < 4; ++mt) acc[mt] = (v4f){binit, binit, binit, binit};
      #pragma unroll
      for (int kk = 0; kk < 4; ++kk) {
        v8s bf = ldfrag(ws, OFS_W2, (wv * 2 + u) * 4 + kk, lane);
        acc[0] = MFMA(a[0][kk], bf, acc[0]);
        acc[1] = MFMA(a[1][kk], bf, acc[1]);
        acc[2] = MFMA(a[2][kk], bf, acc[2]);
        acc[3] = MFMA(a[3][kk], bf, acc[3]);
      }
      float wqh = wq[h];
      #pragma unroll
      for (int mt = 0; mt < 4; ++mt)
        #pragma unroll
        for (int reg = 0; reg < 4; ++reg)
          part[mt * 4 + reg] += sig_f(acc[mt][reg]) * wqh;
    }
    #pragma unroll
    for (int m = 1; m <= 8; m <<= 1)
      #pragma unroll
      for (int i = 0; i < 16; ++i)
        part[i] += __shfl_xor(part[i], m);
    if (r == 0) {
      #pragma unroll
      for (int mt = 0; mt < 4; ++mt)
        #pragma unroll
        for (int reg = 0; reg < 4; ++reg)
          sAPartv[wv * 64 + mt * 16 + q * 4 + reg] = part[mt * 4 + reg];
    }
  }
  __syncthreads();
  if (t < 64) {
    sAlphav[t] = (sAPartv[t] + sAPartv[64 + t] + sAPartv[128 + t] + sAPartv[192 + t])
               * (float)sMaskArr[t];
  }
  __syncthreads();

  // glob partials: seg covers l in [seg*32, seg*32+32)
  {
    float acc = 0.0f;
    #pragma unroll
    for (int l = 0; l < 32; ++l) {
      int ll = seg * 32 + l;
      acc = fmaf(sAlphav[ll], b2f(sH[sAliasRow[ll] * SH_STR + hh]), acc);
    }
    sP[seg * 128 + hh] = acc;
  }
  __syncthreads();
  if (t < HH) sGlobv[t] = sP[t] + sP[128 + t];
  __syncthreads();

  // w3: seg 0 -> local part, seg 1 -> glob part
  {
    const float4* w34 = reinterpret_cast<const float4*>(w3 + (size_t)hh * 256 + seg * 128);
    float a0 = seg ? 0.f : b3[hh], a1 = 0.f, a2v = 0.f, a3 = 0.f;
    if (seg == 0) {
      const uint2* lr = reinterpret_cast<const uint2*>(&sH[lastRow * SH_STR]);
      #pragma unroll 8
      for (int j = 0; j < 32; ++j) {
        float4 w = w34[j]; uint2 v = lr[j];
        a0  = fmaf(b2f_lo(v.x), w.x, a0);  a1 = fmaf(b2f_hi(v.x), w.y, a1);
        a2v = fmaf(b2f_lo(v.y), w.z, a2v); a3 = fmaf(b2f_hi(v.y), w.w, a3);
      }
    } else {
      #pragma unroll 8
      for (int j = 0; j < 32; ++j) {
        float4 w = w34[j];
        a0  = fmaf(sGlobv[4*j+0], w.x, a0);  a1 = fmaf(sGlobv[4*j+1], w.y, a1);
        a2v = fmaf(sGlobv[4*j+2], w.z, a2v); a3 = fmaf(sGlobv[4*j+3], w.w, a3);
      }
    }
    sP[seg * 128 + hh] = (a0 + a1) + (a2v + a3);
  }
  __syncthreads();
  if (t < HH) out[b * HH + t] = sP[t] + sP[128 + t];
}

extern "C" void kernel_launch(void* const* d_in, const int* in_sizes, int n_in,
                              void* d_out, int out_size, void* d_ws, size_t ws_size,
                              hipStream_t stream) {
  const float* A          = (const float*)d_in[0];
  const int*   items      = (const int*)  d_in[1];
  const int*   mask       = (const int*)  d_in[2];
  const int*   alias_in   = (const int*)  d_in[3];
  const float* emb        = (const float*)d_in[4];
  const float* w_in       = (const float*)d_in[5];
  const float* b_in       = (const float*)d_in[6];
  const float* w_out      = (const float*)d_in[7];
  const float* b_out      = (const float*)d_in[8];
  const float* b_iah      = (const float*)d_in[9];
  const float* b_oah      = (const float*)d_in[10];
  const float* wi         = (const float*)d_in[11];
  const float* bi         = (const float*)d_in[12];
  const float* wh         = (const float*)d_in[13];
  const float* bh         = (const float*)d_in[14];
  const float* w1         = (const float*)d_in[15];
  const float* b1         = (const float*)d_in[16];
  const float* w2         = (const float*)d_in[17];
  const float* b2         = (const float*)d_in[18];
  const float* wq         = (const float*)d_in[19];
  const float* w3         = (const float*)d_in[20];
  const float* b3         = (const float*)d_in[21];
  float* out = (float*)d_out;
  uint16_t* wsp = (uint16_t*)d_ws;

  hipLaunchKernelGGL(pack_weights, dim3((N_FRAGS + 255) / 256), dim3(256), 0, stream,
                     w_in, w_out, wi, wh, w2, wsp);
  hipLaunchKernelGGL(srgnn_kernel, dim3(NB), dim3(BDIM), 0, stream,
                     A, items, mask, alias_in, emb,
                     b_in, b_out, b_iah, b_oah, bi, bh,
                     w1, b1, b2, wq, w3, b3, wsp, out);
}